// Round 1
// baseline (149.996 us; speedup 1.0000x reference)
//
#include <hip/hip_runtime.h>
#include <math.h>

#define WPB 4  // waves (trajectories) per block

static __device__ __forceinline__ float wsum(float x){
#pragma unroll
  for (int off = 32; off > 0; off >>= 1) x += __shfl_xor(x, off, 64);
  return x;
}
static __device__ __forceinline__ float wmaxr(float x){
#pragma unroll
  for (int off = 32; off > 0; off >>= 1) x = fmaxf(x, __shfl_xor(x, off, 64));
  return x;
}
static __device__ __forceinline__ float wminr(float x){
#pragma unroll
  for (int off = 32; off > 0; off >>= 1) x = fminf(x, __shfl_xor(x, off, 64));
  return x;
}
static __device__ __forceinline__ float lane_bcastf(float x, int l){
  return __uint_as_float(__builtin_amdgcn_readlane(__float_as_uint(x), l));
}
static __device__ __forceinline__ float first_lanef(float x){
  return __uint_as_float(__builtin_amdgcn_readfirstlane(__float_as_uint(x)));
}

__global__ __launch_bounds__(WPB * 64)
void traj_kernel(const float* __restrict__ coords,
                 const int* __restrict__ lengths,
                 const float* __restrict__ W,
                 const float* __restrict__ bias,
                 const float* __restrict__ lnw,
                 const float* __restrict__ lnb,
                 float* __restrict__ out, int B)
{
  const int i = threadIdx.x & 63;                      // lane = row / delta index
  const int b = blockIdx.x * WPB + (threadIdx.x >> 6); // trajectory
  if (b >= B) return;

  const int n = __builtin_amdgcn_readfirstlane(lengths[b]); // 4..48, wave-uniform
  const int m = n - 1;                                      // #deltas, 3..47
  const float* cp = coords + (size_t)b * 480;

  // ---- load row i (40B, 8-aligned) ----
  float c[10];
  if (i < 48) {
    const float2* p = reinterpret_cast<const float2*>(cp + i * 10);
    float2 v0 = p[0], v1 = p[1], v2 = p[2], v3 = p[3], v4 = p[4];
    c[0]=v0.x; c[1]=v0.y; c[2]=v1.x; c[3]=v1.y; c[4]=v2.x;
    c[5]=v2.y; c[6]=v3.x; c[7]=v3.y; c[8]=v4.x; c[9]=v4.y;
  } else {
#pragma unroll
    for (int k = 0; k < 10; k++) c[k] = 0.f;
  }

  // ---- delta_i = row_{i+1} - row_i, masked i<m ----
  const bool dact = (i < m);
  float d[10];
  float dsq = 0.f;
#pragma unroll
  for (int k = 0; k < 10; k++) {
    float cn = __shfl_down(c[k], 1, 64);
    float dd = dact ? (cn - c[k]) : 0.f;
    d[k] = dd;
    dsq = fmaf(dd, dd, dsq);
  }
  const float dmag = (dsq > 0.f) ? sqrtf(fmaxf(dsq, 1e-30f)) : 0.f; // safe_norm
  const float na   = fmaxf(dmag, 1e-8f);                            // COS_EPS
  const float inv  = 1.0f / na;

  // ---- cos_i = <d_i, d_{i+1}> / (na_i * na_{i+1}), masked i<n-2 ----
  float dot = 0.f;
#pragma unroll
  for (int k = 0; k < 10; k++) {
    float dn = __shfl_down(d[k], 1, 64);
    dot = fmaf(d[k], dn, dot);
  }
  const float invn = __shfl_down(inv, 1, 64);
  const bool cact = (i < n - 2);
  const float cosv   = dot * inv * invn;
  const float curv   = 1.f - cosv;
  const float curv_m = cact ? curv : 0.f;
  const float cos_m  = cact ? cosv : 0.f;

  // ---- wave reductions ----
  const int half = m >> 1;
  const float dmv = dmag;                       // already 0 where !dact
  const float path_len = wsum(dmv);
  const float sum_dm2  = wsum(dmv * dmv);
  const float max_dm   = wmaxr(dmv);            // dmv>=0, identity 0 ok
  const float sum_f    = wsum((i < half + 1) ? dmv : 0.f);
  const float sum_s    = wsum((i >= half) ? dmv : 0.f); // i<m implicit via dmv

  const float sum_cv  = wsum(curv_m);
  const float sum_cv2 = wsum(curv_m * curv_m);
  const float max_cv  = wmaxr(cact ? curv : -INFINITY);
  const float min_cv  = wminr(cact ? curv :  INFINITY);
  const float sum_cs  = wsum(cos_m);
  const float min_cs  = wminr(cact ? cosv :  INFINITY);
  const float sum_ng  = wsum((cact && cosv < 0.f) ? 1.f : 0.f);

  // parallelism: sum_{i<j<m} u_i.u_j = (|sum u|^2 - sum|u|^2)/2,  u = d/na
  float Usq = 0.f;
#pragma unroll
  for (int k = 0; k < 10; k++) {
    float Uk = wsum(d[k] * inv);
    Usq = fmaf(Uk, Uk, Usq);
  }
  const float sum_uu = wsum(dsq * (inv * inv));

  // coord stats over rows i<n
  float csl = 0.f, cs2l = 0.f;
  if (i < n) {
#pragma unroll
    for (int k = 0; k < 10; k++) { csl += c[k]; cs2l = fmaf(c[k], c[k], cs2l); }
  }
  const float sum_c  = wsum(csl);
  const float sum_c2 = wsum(cs2l);

  // total displacement ||row_{n-1} - row_0||
  float tsql = 0.f;
#pragma unroll
  for (int k = 0; k < 10; k++) {
    float c0 = lane_bcastf(c[k], 0);
    float t = c[k] - c0;
    tsql = fmaf(t, t, tsql);
  }
  const float tsq = lane_bcastf(tsql, m);       // lane m = row n-1
  const float total_disp = (tsq > 0.f) ? sqrtf(fmaxf(tsq, 1e-30f)) : 0.f;

  // ---- scalar features (wave-uniform) ----
  const float EPSf = 1e-9f;
  const float nf = (float)n, mf = (float)m, ncf = (float)(n - 2);
  const float disp_ratio = total_disp / (path_len + EPSf);
  const float mean_cv = sum_cv / ncf;
  const float cv_var  = (sum_cv2 - ncf * mean_cv * mean_cv) / fmaxf(ncf - 1.f, 1.f);
  const float std_cv  = sqrtf(fmaxf(cv_var, 1e-30f));   // ncf>=2 always
  const float mean_cs = sum_cs / ncf;
  const float dirchg  = sum_ng / fmaxf(ncf, 1.f);
  const float fh = sum_f / (float)(half + 1);
  const float sh = sum_s / (float)(m - half);
  const float conv = (fh - sh) / (fh + EPSf);
  const float casc = (sh - fh) / (fh + EPSf);
  const float npairs = mf * (mf - 1.f) * 0.5f;
  const float par = 0.5f * (Usq - sum_uu) / fmaxf(npairs, 1.f);
  const float mean_dm = path_len / mf;
  const float dm_var = (sum_dm2 - mf * mean_dm * mean_dm) / fmaxf(mf - 1.f, 1.f);
  const float std_dm = sqrtf(fmaxf(dm_var, 1e-30f));    // mf>=3 always
  const float jump = (mean_dm > EPSf) ? (max_dm / mean_dm) : 1.f;
  const float cnt = nf * 10.f;
  const float mean_co = sum_c / cnt;
  const float co_var = (sum_c2 - cnt * mean_co * mean_co) / (cnt - 1.f);
  const float std_co = sqrtf(fmaxf(co_var, 1e-30f));

  // ---- assemble 60 features; push to SGPRs via readlane/readfirstlane ----
  float feat[60];
  feat[0]  = first_lanef(total_disp);
  feat[1]  = first_lanef(path_len);
  feat[2]  = first_lanef(disp_ratio);
  feat[3]  = nf * 0.1f;
  feat[4]  = first_lanef(mean_cv);
  feat[5]  = first_lanef(max_cv);
  feat[6]  = first_lanef(std_cv);
  feat[7]  = first_lanef(max_cv - min_cv);
  feat[8]  = first_lanef(mean_cs);
  feat[9]  = first_lanef(min_cs);
  feat[10] = first_lanef(dirchg);
  feat[11] = feat[2];            // linearity == disp_ratio
  feat[12] = 1.f - feat[2];      // loop_score
  feat[13] = first_lanef(conv);
  feat[14] = first_lanef(par);
  feat[15] = first_lanef(jump);
  feat[16] = first_lanef(casc);
  feat[17] = first_lanef(mean_dm);
  feat[18] = first_lanef(std_dm);
  feat[19] = first_lanef(mean_co);
  feat[20] = first_lanef(std_co);
#pragma unroll
  for (int r = 0; r < 3; r++)
#pragma unroll
    for (int k = 0; k < 10; k++)
      feat[21 + r * 10 + k] = lane_bcastf(d[k], r);   // padded_deltas (m>=3)
#pragma unroll
  for (int r = 0; r < 9; r++)
    feat[51 + r] = lane_bcastf(curv_m, r);            // padded_curvs (masked)

  // ---- h = feat @ W + b (lane j computes h_j) ----
  float h = 0.f;
  if (i < 48) {
    h = bias[i];
#pragma unroll
    for (int f = 0; f < 60; ++f) h = fmaf(feat[f], W[f * 48 + i], h);
  }

  // ---- LayerNorm over 48 outputs ----
  const float hm = (i < 48) ? h : 0.f;
  const float s1 = wsum(hm);
  const float s2 = wsum(hm * hm);
  const float mu  = s1 * (1.f / 48.f);
  const float var = s2 * (1.f / 48.f) - mu * mu;

  if (i < 48) {
    float x = (h - mu) / sqrtf(var + 1e-5f) * lnw[i] + lnb[i];
    float g = 0.5f * x * (1.f + erff(x * 0.70710678118654752f)); // exact gelu
    out[(size_t)b * 48 + i] = g;
  }
}

extern "C" void kernel_launch(void* const* d_in, const int* in_sizes, int n_in,
                              void* d_out, int out_size, void* d_ws, size_t ws_size,
                              hipStream_t stream)
{
  const float* coords = (const float*)d_in[0];
  const int*   lengths= (const int*)d_in[1];
  const float* W      = (const float*)d_in[2];
  const float* bias   = (const float*)d_in[3];
  const float* lnw    = (const float*)d_in[4];
  const float* lnb    = (const float*)d_in[5];
  float* out = (float*)d_out;

  const int B = in_sizes[1];                 // 32768 trajectories
  const int blocks = (B + WPB - 1) / WPB;
  traj_kernel<<<blocks, WPB * 64, 0, stream>>>(coords, lengths, W, bias, lnw, lnb, out, B);
}

// Round 2
// 126.438 us; speedup vs baseline: 1.1863x; 1.1863x over previous
//
#include <hip/hip_runtime.h>
#include <math.h>

#define WPB 4  // waves (trajectories) per block

// ---- DPP wave64 reductions (pure VALU, no DS) ----
template<int CTRL, int RM>
static __device__ __forceinline__ float dppadd(float x){
  int t = __builtin_amdgcn_update_dpp(0, __float_as_int(x), CTRL, RM, 0xf, true);
  return x + __int_as_float(t);
}
template<int CTRL, int RM>
static __device__ __forceinline__ float dppmax(float x){
  int t = __builtin_amdgcn_update_dpp(__float_as_int(x), __float_as_int(x), CTRL, RM, 0xf, false);
  return fmaxf(x, __int_as_float(t));
}
template<int CTRL, int RM>
static __device__ __forceinline__ float dppmin(float x){
  int t = __builtin_amdgcn_update_dpp(__float_as_int(x), __float_as_int(x), CTRL, RM, 0xf, false);
  return fminf(x, __int_as_float(t));
}
static __device__ __forceinline__ float rl(float x, int l){
  return __uint_as_float(__builtin_amdgcn_readlane(__float_as_uint(x), l));
}
// full-wave sum, result broadcast (uniform) via readlane 63
static __device__ __forceinline__ float wsum(float x){
  x = dppadd<0x111,0xf>(x);  // row_shr:1
  x = dppadd<0x112,0xf>(x);  // row_shr:2
  x = dppadd<0x114,0xf>(x);  // row_shr:4
  x = dppadd<0x118,0xf>(x);  // row_shr:8
  x = dppadd<0x142,0xa>(x);  // row_bcast:15 -> rows 1,3
  x = dppadd<0x143,0xc>(x);  // row_bcast:31 -> rows 2,3
  return rl(x, 63);
}
static __device__ __forceinline__ float wmax(float x){
  x = dppmax<0x111,0xf>(x); x = dppmax<0x112,0xf>(x);
  x = dppmax<0x114,0xf>(x); x = dppmax<0x118,0xf>(x);
  x = dppmax<0x142,0xa>(x); x = dppmax<0x143,0xc>(x);
  return rl(x, 63);
}
static __device__ __forceinline__ float wmin(float x){
  x = dppmin<0x111,0xf>(x); x = dppmin<0x112,0xf>(x);
  x = dppmin<0x114,0xf>(x); x = dppmin<0x118,0xf>(x);
  x = dppmin<0x142,0xa>(x); x = dppmin<0x143,0xc>(x);
  return rl(x, 63);
}
static __device__ __forceinline__ float frcp(float x){ return __builtin_amdgcn_rcpf(x); }
static __device__ __forceinline__ float fsqrt(float x){ return __builtin_amdgcn_sqrtf(x); }

__global__ void transpose_w(const float* __restrict__ W, float* __restrict__ Wt){
  int idx = blockIdx.x * 256 + threadIdx.x;
  if (idx < 60 * 48) { int f = idx / 48, j = idx - f * 48; Wt[j * 60 + f] = W[idx]; }
}

template<bool USEWT>
__global__ __launch_bounds__(WPB * 64)
void traj_kernel(const float* __restrict__ coords,
                 const int* __restrict__ lengths,
                 const float* __restrict__ Wsrc,   // Wt [48][60] if USEWT else W [60][48]
                 const float* __restrict__ bias,
                 const float* __restrict__ lnw,
                 const float* __restrict__ lnb,
                 float* __restrict__ out, int B)
{
  const int i = threadIdx.x & 63;
  const int b = blockIdx.x * WPB + (threadIdx.x >> 6);
  if (b >= B) return;

  const int n = __builtin_amdgcn_readfirstlane(lengths[b]); // 4..48, wave-uniform
  const int m = n - 1;
  const float* cp = coords + (size_t)b * 480;

  // rows i and i+1 (always in-bounds of the 48-row slab)
  float c[10], cnx[10];
  if (i < 48) {
    const float2* p = reinterpret_cast<const float2*>(cp + i * 10);
    float2 v0 = p[0], v1 = p[1], v2 = p[2], v3 = p[3], v4 = p[4];
    c[0]=v0.x; c[1]=v0.y; c[2]=v1.x; c[3]=v1.y; c[4]=v2.x;
    c[5]=v2.y; c[6]=v3.x; c[7]=v3.y; c[8]=v4.x; c[9]=v4.y;
  } else {
#pragma unroll
    for (int k = 0; k < 10; k++) c[k] = 0.f;
  }
  if (i < 47) {
    const float2* p = reinterpret_cast<const float2*>(cp + (i + 1) * 10);
    float2 v0 = p[0], v1 = p[1], v2 = p[2], v3 = p[3], v4 = p[4];
    cnx[0]=v0.x; cnx[1]=v0.y; cnx[2]=v1.x; cnx[3]=v1.y; cnx[4]=v2.x;
    cnx[5]=v2.y; cnx[6]=v3.x; cnx[7]=v3.y; cnx[8]=v4.x; cnx[9]=v4.y;
  } else {
#pragma unroll
    for (int k = 0; k < 10; k++) cnx[k] = 0.f;
  }

  // delta_i, masked i<m
  const bool dact = (i < m);
  float d[10]; float dsq = 0.f;
#pragma unroll
  for (int k = 0; k < 10; k++) {
    float dd = dact ? (cnx[k] - c[k]) : 0.f;
    d[k] = dd;
    dsq = fmaf(dd, dd, dsq);
  }
  const float dmag = (dsq > 0.f) ? fsqrt(fmaxf(dsq, 1e-30f)) : 0.f;
  const float na   = fmaxf(dmag, 1e-8f);
  const float inv  = frcp(na);

  // neighbor dot via shfl_down (DS pipe is otherwise idle)
  float dot = 0.f;
#pragma unroll
  for (int k = 0; k < 10; k++) {
    float dn = __shfl_down(d[k], 1, 64);
    dot = fmaf(d[k], dn, dot);
  }
  const float invn = __shfl_down(inv, 1, 64);
  const bool cact = (i < n - 2);
  const float cosv  = dot * inv * invn;
  const float cos_m = cact ? cosv : 0.f;

  // ---- reductions (DPP) ----
  const int half = m >> 1;
  const float path_len = wsum(dmag);
  const float sum_dm2  = wsum(dsq);
  const float max_dm   = wmax(dmag);
  const float sum_f    = wsum((i <= half) ? dmag : 0.f);
  const float dm_half  = __uint_as_float(__builtin_amdgcn_readlane(__float_as_uint(dmag), half));
  const float sum_s    = path_len + dm_half - sum_f;

  const float sum_cos  = wsum(cos_m);
  const float sum_cos2 = wsum(cos_m * cos_m);
  const float max_cos  = wmax(cact ? cosv : -INFINITY);
  const float min_cos  = wmin(cact ? cosv :  INFINITY);
  const float sum_ng   = wsum((cact && cosv < 0.f) ? 1.f : 0.f);

  // parallelism: sum_{i<j<m} u_i.u_j = (|sum u|^2 - sum u.u)/2
  float Usq = 0.f;
#pragma unroll
  for (int k = 0; k < 10; k++) {
    float Uk = wsum(d[k] * inv);
    Usq = fmaf(Uk, Uk, Usq);
  }
  const float sum_uu = wsum(dsq * (inv * inv));

  // coord stats over rows i<n
  float csl = 0.f, cs2l = 0.f;
  if (i < n) {
#pragma unroll
    for (int k = 0; k < 10; k++) { csl += c[k]; cs2l = fmaf(c[k], c[k], cs2l); }
  }
  const float sum_c  = wsum(csl);
  const float sum_c2 = wsum(cs2l);

  // total displacement ||row_{n-1} - row_0||
  float tsql = 0.f;
#pragma unroll
  for (int k = 0; k < 10; k++) {
    float c0 = rl(c[k], 0);
    float t = c[k] - c0;
    tsql = fmaf(t, t, tsql);
  }
  const float tdq = __uint_as_float(__builtin_amdgcn_readlane(__float_as_uint(tsql), m));
  const float total_disp = (tdq > 0.f) ? fsqrt(fmaxf(tdq, 1e-30f)) : 0.f;

  // ---- scalar features (wave-uniform values) ----
  const float EPSf = 1e-9f;
  const float nf = (float)n, mf = (float)m, ncf = (float)(n - 2);
  const float rncf = frcp(ncf);
  const float disp_ratio = total_disp * frcp(path_len + EPSf);
  const float sum_cv  = ncf - sum_cos;
  const float mean_cv = sum_cv * rncf;
  const float sum_cv2 = fmaf(-2.f, sum_cos, ncf) + sum_cos2;
  const float cv_var  = (sum_cv2 - ncf * mean_cv * mean_cv) * frcp(fmaxf(ncf - 1.f, 1.f));
  const float std_cv  = fsqrt(fmaxf(cv_var, 1e-30f));
  const float max_cv  = 1.f - min_cos;
  const float cv_rng  = max_cos - min_cos;
  const float mean_cs = sum_cos * rncf;
  const float dirchg  = sum_ng * rncf;
  const float fh = sum_f * frcp((float)(half + 1));
  const float sh = sum_s * frcp((float)(m - half));
  const float conv = (fh - sh) * frcp(fh + EPSf);
  const float npairs = mf * (mf - 1.f) * 0.5f;
  const float par = (Usq - sum_uu) * 0.5f * frcp(npairs);
  const float mean_dm = path_len * frcp(mf);
  const float dm_var = (sum_dm2 - mf * mean_dm * mean_dm) * frcp(mf - 1.f);
  const float std_dm = fsqrt(fmaxf(dm_var, 1e-30f));
  const float jump = (mean_dm > EPSf) ? max_dm * frcp(mean_dm) : 1.f;
  const float cnt = nf * 10.f;
  const float mean_co = sum_c * frcp(cnt);
  const float co_var = (sum_c2 - cnt * mean_co * mean_co) * frcp(cnt - 1.f);
  const float std_co = fsqrt(fmaxf(co_var, 1e-30f));

  // ---- 60 features ----
  float feat[60];
  feat[0]  = total_disp;
  feat[1]  = path_len;
  feat[2]  = disp_ratio;
  feat[3]  = nf * 0.1f;
  feat[4]  = mean_cv;
  feat[5]  = max_cv;
  feat[6]  = std_cv;
  feat[7]  = cv_rng;
  feat[8]  = mean_cs;
  feat[9]  = min_cos;
  feat[10] = dirchg;
  feat[11] = disp_ratio;        // linearity
  feat[12] = 1.f - disp_ratio;  // loop_score
  feat[13] = conv;
  feat[14] = par;
  feat[15] = jump;
  feat[16] = -conv;             // cascade (bit-exact negation)
  feat[17] = mean_dm;
  feat[18] = std_dm;
  feat[19] = mean_co;
  feat[20] = std_co;
#pragma unroll
  for (int r = 0; r < 3; r++)
#pragma unroll
    for (int k = 0; k < 10; k++)
      feat[21 + r * 10 + k] = rl(d[k], r);        // padded_deltas (m>=3 so rows 0..2 valid)
  const float curv_m = cact ? (1.f - cosv) : 0.f;
#pragma unroll
  for (int r = 0; r < 9; r++)
    feat[51 + r] = rl(curv_m, r);                 // padded_curvs (masked)

  // ---- h = feat @ W + b (lane j computes h_j) ----
  float h = 0.f;
  if (i < 48) {
    h = bias[i];
    if (USEWT) {
      const float4* wr = reinterpret_cast<const float4*>(Wsrc + i * 60);
#pragma unroll
      for (int q = 0; q < 15; ++q) {
        float4 w = wr[q];
        h = fmaf(feat[4 * q + 0], w.x, h);
        h = fmaf(feat[4 * q + 1], w.y, h);
        h = fmaf(feat[4 * q + 2], w.z, h);
        h = fmaf(feat[4 * q + 3], w.w, h);
      }
    } else {
#pragma unroll
      for (int f = 0; f < 60; ++f) h = fmaf(feat[f], Wsrc[f * 48 + i], h);
    }
  }

  // ---- LayerNorm + exact GELU ----
  const float hm = (i < 48) ? h : 0.f;
  const float s1 = wsum(hm);
  const float s2 = wsum(hm * hm);
  const float mu  = s1 * (1.f / 48.f);
  const float var = fmaf(-mu, mu, s2 * (1.f / 48.f));

  if (i < 48) {
    float x = (h - mu) * __builtin_amdgcn_rsqf(var + 1e-5f) * lnw[i] + lnb[i];
    float g = 0.5f * x * (1.f + erff(x * 0.70710678118654752f));
    out[(size_t)b * 48 + i] = g;
  }
}

extern "C" void kernel_launch(void* const* d_in, const int* in_sizes, int n_in,
                              void* d_out, int out_size, void* d_ws, size_t ws_size,
                              hipStream_t stream)
{
  const float* coords = (const float*)d_in[0];
  const int*   lengths= (const int*)d_in[1];
  const float* W      = (const float*)d_in[2];
  const float* bias   = (const float*)d_in[3];
  const float* lnw    = (const float*)d_in[4];
  const float* lnb    = (const float*)d_in[5];
  float* out = (float*)d_out;

  const int B = in_sizes[1];
  const int blocks = (B + WPB - 1) / WPB;

  if (ws_size >= (size_t)(60 * 48 * sizeof(float))) {
    float* Wt = (float*)d_ws;
    transpose_w<<<12, 256, 0, stream>>>(W, Wt);
    traj_kernel<true><<<blocks, WPB * 64, 0, stream>>>(coords, lengths, Wt, bias, lnw, lnb, out, B);
  } else {
    traj_kernel<false><<<blocks, WPB * 64, 0, stream>>>(coords, lengths, W, bias, lnw, lnb, out, B);
  }
}

// Round 3
// 122.276 us; speedup vs baseline: 1.2267x; 1.0340x over previous
//
#include <hip/hip_runtime.h>
#include <math.h>

static __device__ __forceinline__ float frcp(float x){ return __builtin_amdgcn_rcpf(x); }
static __device__ __forceinline__ float fsq (float x){ return __builtin_amdgcn_sqrtf(x); }

// ---- DPP row-of-16 reductions (verified prefix of round-2 pattern) ----
template<int CTRL>
static __device__ __forceinline__ float dppadd(float x){
  int t = __builtin_amdgcn_update_dpp(0, __float_as_int(x), CTRL, 0xf, 0xf, true);
  return x + __int_as_float(t);
}
template<int CTRL>
static __device__ __forceinline__ float dppmax(float x){
  int t = __builtin_amdgcn_update_dpp(__float_as_int(x), __float_as_int(x), CTRL, 0xf, 0xf, false);
  return fmaxf(x, __int_as_float(t));
}
template<int CTRL>
static __device__ __forceinline__ float dppmin(float x){
  int t = __builtin_amdgcn_update_dpp(__float_as_int(x), __float_as_int(x), CTRL, 0xf, 0xf, false);
  return fminf(x, __int_as_float(t));
}
// row sum -> broadcast row-wide via ds_swizzle (lane' = (lane&0x10)|0xF : slot 15)
static __device__ __forceinline__ float rsum16(float x){
  x = dppadd<0x111>(x); x = dppadd<0x112>(x);
  x = dppadd<0x114>(x); x = dppadd<0x118>(x);
  return __int_as_float(__builtin_amdgcn_ds_swizzle(__float_as_int(x), 0x1F0));
}
static __device__ __forceinline__ float rmax16(float x){
  x = dppmax<0x111>(x); x = dppmax<0x112>(x);
  x = dppmax<0x114>(x); x = dppmax<0x118>(x);
  return __int_as_float(__builtin_amdgcn_ds_swizzle(__float_as_int(x), 0x1F0));
}
static __device__ __forceinline__ float rmin16(float x){
  x = dppmin<0x111>(x); x = dppmin<0x112>(x);
  x = dppmin<0x114>(x); x = dppmin<0x118>(x);
  return __int_as_float(__builtin_amdgcn_ds_swizzle(__float_as_int(x), 0x1F0));
}
// broadcast slot P of each row of 16: lane' = (lane&0x10)|P  (P must be literal)
#define BC(P, x) __int_as_float(__builtin_amdgcn_ds_swizzle(__float_as_int(x), 0x10 | ((P) << 5)))

__global__ void transpose_w(const float* __restrict__ W, float* __restrict__ Wt){
  int idx = blockIdx.x * 256 + threadIdx.x;
  if (idx < 60 * 48) { int f = idx / 48, j = idx - f * 48; Wt[j * 60 + f] = W[idx]; }
}

template<bool USEWT>
__global__ __launch_bounds__(256)
void traj_kernel(const float* __restrict__ coords,
                 const int* __restrict__ lengths,
                 const float* __restrict__ Wsrc,   // Wt [48][60] if USEWT else W [60][48]
                 const float* __restrict__ bias,
                 const float* __restrict__ lnw,
                 const float* __restrict__ lnb,
                 float* __restrict__ out, int B)
{
  const int lane = threadIdx.x & 63;
  const int s    = lane & 15;                       // slot within row of 16
  const int grp  = (blockIdx.x * 4 + (threadIdx.x >> 6)) * 4 + (lane >> 4);
  const bool bvalid = (grp < B);
  const int b = bvalid ? grp : (B - 1);

  const int n = lengths[b];                         // row-uniform VGPR, 4..48
  const int m = n - 1;
  const float* cp = coords + (size_t)b * 480;

  // ---- load rows j=16q+s and j+1 ----
  float c[3][10], cn[3][10];
#pragma unroll
  for (int q = 0; q < 3; ++q) {
    const float2* p = reinterpret_cast<const float2*>(cp + (q * 16 + s) * 10);
#pragma unroll
    for (int k = 0; k < 5; ++k) { float2 v = p[k]; c[q][2*k] = v.x; c[q][2*k+1] = v.y; }
  }
#pragma unroll
  for (int q = 0; q < 3; ++q) {
    const int row = q * 16 + s + 1;
    if (row < 48) {
      const float2* p = reinterpret_cast<const float2*>(cp + row * 10);
#pragma unroll
      for (int k = 0; k < 5; ++k) { float2 v = p[k]; cn[q][2*k] = v.x; cn[q][2*k+1] = v.y; }
    } else {
#pragma unroll
      for (int k = 0; k < 10; ++k) cn[q][k] = 0.f;
    }
  }

  // ---- coord stats over rows < n ----
  float csl = 0.f, cs2l = 0.f;
#pragma unroll
  for (int q = 0; q < 3; ++q) {
    float t1 = 0.f, t2 = 0.f;
#pragma unroll
    for (int k = 0; k < 10; ++k) { t1 += c[q][k]; t2 = fmaf(c[q][k], c[q][k], t2); }
    const bool act = (q * 16 + s) < n;
    csl  += act ? t1 : 0.f;
    cs2l += act ? t2 : 0.f;
  }
  const float sum_c  = rsum16(csl);
  const float sum_c2 = rsum16(cs2l);

  // ---- total displacement: ||row_{n-1} - row_0|| ----
  float cc0[10];
#pragma unroll
  for (int k = 0; k < 10; ++k) cc0[k] = BC(0, c[0][k]);
  const int qs = (n - 1) >> 4, ssl = (n - 1) & 15;
  float tql = 0.f;
#pragma unroll
  for (int q = 0; q < 3; ++q) {
    float tq = 0.f;
#pragma unroll
    for (int k = 0; k < 10; ++k) { float t = c[q][k] - cc0[k]; tq = fmaf(t, t, tq); }
    tql = (s == ssl && q == qs) ? tq : tql;
  }
  const float tdq = rsum16(tql);                    // single contributing lane per row
  const float total_disp = (tdq > 0.f) ? fsq(fmaxf(tdq, 1e-30f)) : 0.f;

  // ---- deltas ----
  const int half = m >> 1;
  float d[3][10], inv[3];
  float path_l=0.f, dm2_l=0.f, maxdm_l=0.f, sf_l=0.f, ss_l=0.f, uu_l=0.f;
  float uk[10];
#pragma unroll
  for (int k = 0; k < 10; ++k) uk[k] = 0.f;
#pragma unroll
  for (int q = 0; q < 3; ++q) {
    const int j = q * 16 + s;
    float ds_ = 0.f;
#pragma unroll
    for (int k = 0; k < 10; ++k) { float dd = cn[q][k] - c[q][k]; d[q][k] = dd; ds_ = fmaf(dd, dd, ds_); }
    const float sn = (ds_ > 0.f) ? fsq(fmaxf(ds_, 1e-30f)) : 0.f;   // safe_norm
    inv[q] = frcp(fmaxf(sn, 1e-8f));                                // 1/na
    const bool jm = j < m;
    const float dm = jm ? sn : 0.f;
    path_l += dm;
    dm2_l  += jm ? ds_ : 0.f;
    maxdm_l = fmaxf(maxdm_l, dm);
    sf_l += (j <= half) ? dm : 0.f;
    ss_l += (j >= half) ? dm : 0.f;
    const float invm = jm ? inv[q] : 0.f;
#pragma unroll
    for (int k = 0; k < 10; ++k) uk[k] = fmaf(d[q][k], invm, uk[k]);
    uu_l = fmaf(ds_ * invm, invm, uu_l);
  }

  // ---- neighbor inv via ds_bpermute rotate-within-row (lane <- lane+1 mod 16) ----
  const int rotb = (((lane & 48) | ((lane + 1) & 15)) << 2);
  const float rinv0 = __int_as_float(__builtin_amdgcn_ds_bpermute(rotb, __float_as_int(inv[0])));
  const float rinv1 = __int_as_float(__builtin_amdgcn_ds_bpermute(rotb, __float_as_int(inv[1])));
  const float rinv2 = __int_as_float(__builtin_amdgcn_ds_bpermute(rotb, __float_as_int(inv[2])));
  float invn[3];
  invn[0] = (s < 15) ? rinv0 : rinv1;   // s=15: delta j+1 = chunk q+1 slot 0
  invn[1] = (s < 15) ? rinv1 : rinv2;
  invn[2] = (s < 15) ? rinv2 : 0.f;     // j=47 never active

  // ---- cos / curvature (d_{j+1} recomputed from loaded rows j+1, j+2) ----
  float cos_l=0.f, cos2_l=0.f, ng_l=0.f, maxc_l=-INFINITY, minc_l=INFINITY;
  float curv0 = 0.f;
#pragma unroll
  for (int q = 0; q < 3; ++q) {
    const int j = q * 16 + s;
    float dn[10];
    if (j + 2 < 48) {
      const float2* p = reinterpret_cast<const float2*>(cp + (j + 2) * 10);
#pragma unroll
      for (int k = 0; k < 5; ++k) { float2 v = p[k]; dn[2*k] = v.x - cn[q][2*k]; dn[2*k+1] = v.y - cn[q][2*k+1]; }
    } else {
#pragma unroll
      for (int k = 0; k < 10; ++k) dn[k] = 0.f;
    }
    float dot = 0.f;
#pragma unroll
    for (int k = 0; k < 10; ++k) dot = fmaf(d[q][k], dn[k], dot);
    const float cosv = dot * inv[q] * invn[q];
    const bool ca = j < (n - 2);
    const float cm = ca ? cosv : 0.f;
    cos_l += cm;
    cos2_l = fmaf(cm, cm, cos2_l);
    maxc_l = fmaxf(maxc_l, ca ? cosv : -INFINITY);
    minc_l = fminf(minc_l, ca ? cosv :  INFINITY);
    ng_l += (cm < 0.f) ? 1.f : 0.f;
    if (q == 0) curv0 = ca ? (1.f - cosv) : 0.f;
  }

  // ---- row reductions ----
  const float path_len = rsum16(path_l);
  const float sum_dm2  = rsum16(dm2_l);
  const float max_dm   = rmax16(maxdm_l);
  const float sum_f    = rsum16(sf_l);
  const float sum_s    = rsum16(ss_l);
  const float sum_cos  = rsum16(cos_l);
  const float sum_cos2 = rsum16(cos2_l);
  const float sum_ng   = rsum16(ng_l);
  const float max_cos  = rmax16(maxc_l);
  const float min_cos  = rmin16(minc_l);
  float Usq = 0.f;
#pragma unroll
  for (int k = 0; k < 10; ++k) { float Uk = rsum16(uk[k]); Usq = fmaf(Uk, Uk, Usq); }
  const float sum_uu = rsum16(uu_l);

  // ---- scalar features (row-uniform VGPR values) ----
  const float EPSf = 1e-9f;
  const float nf = (float)n, mf = (float)m, ncf = (float)(n - 2);
  const float rncf = frcp(ncf);
  const float disp_ratio = total_disp * frcp(path_len + EPSf);
  const float sum_cv  = ncf - sum_cos;
  const float mean_cv = sum_cv * rncf;
  const float sum_cv2 = fmaf(-2.f, sum_cos, ncf) + sum_cos2;
  const float cv_var  = (sum_cv2 - ncf * mean_cv * mean_cv) * frcp(fmaxf(ncf - 1.f, 1.f));
  const float std_cv  = fsq(fmaxf(cv_var, 1e-30f));
  const float max_cv  = 1.f - min_cos;
  const float cv_rng  = max_cos - min_cos;
  const float mean_cs = sum_cos * rncf;
  const float dirchg  = sum_ng * rncf;
  const float fh = sum_f * frcp((float)(half + 1));
  const float sh = sum_s * frcp((float)(m - half));
  const float conv = (fh - sh) * frcp(fh + EPSf);
  const float npairs = mf * (mf - 1.f) * 0.5f;
  const float par = (Usq - sum_uu) * 0.5f * frcp(npairs);
  const float mean_dm = path_len * frcp(mf);
  const float dm_var = (sum_dm2 - mf * mean_dm * mean_dm) * frcp(mf - 1.f);
  const float std_dm = fsq(fmaxf(dm_var, 1e-30f));
  const float jump = (mean_dm > EPSf) ? max_dm * frcp(mean_dm) : 1.f;
  const float cnt = nf * 10.f;
  const float mean_co = sum_c * frcp(cnt);
  const float co_var = (sum_c2 - cnt * mean_co * mean_co) * frcp(cnt - 1.f);
  const float std_co = fsq(fmaxf(co_var, 1e-30f));

  // ---- 60 features (row-uniform in VGPRs) ----
  float feat[60];
  feat[0]  = total_disp;
  feat[1]  = path_len;
  feat[2]  = disp_ratio;
  feat[3]  = nf * 0.1f;
  feat[4]  = mean_cv;
  feat[5]  = max_cv;
  feat[6]  = std_cv;
  feat[7]  = cv_rng;
  feat[8]  = mean_cs;
  feat[9]  = min_cos;
  feat[10] = dirchg;
  feat[11] = disp_ratio;
  feat[12] = 1.f - disp_ratio;
  feat[13] = conv;
  feat[14] = par;
  feat[15] = jump;
  feat[16] = -conv;
  feat[17] = mean_dm;
  feat[18] = std_dm;
  feat[19] = mean_co;
  feat[20] = std_co;
#pragma unroll
  for (int k = 0; k < 10; ++k) feat[21 + k] = BC(0, d[0][k]);   // delta row 0
#pragma unroll
  for (int k = 0; k < 10; ++k) feat[31 + k] = BC(1, d[0][k]);   // delta row 1
#pragma unroll
  for (int k = 0; k < 10; ++k) feat[41 + k] = BC(2, d[0][k]);   // delta row 2
  feat[51] = BC(0, curv0); feat[52] = BC(1, curv0); feat[53] = BC(2, curv0);
  feat[54] = BC(3, curv0); feat[55] = BC(4, curv0); feat[56] = BC(5, curv0);
  feat[57] = BC(6, curv0); feat[58] = BC(7, curv0); feat[59] = BC(8, curv0);

  // ---- h_j = feat @ W + b for j = s, s+16, s+32 ----
  float h[3];
#pragma unroll
  for (int q = 0; q < 3; ++q) {
    const int j = q * 16 + s;
    float acc = bias[j];
    if (USEWT) {
      const float4* wr = reinterpret_cast<const float4*>(Wsrc + j * 60);
#pragma unroll
      for (int t = 0; t < 15; ++t) {
        float4 w = wr[t];
        acc = fmaf(feat[4*t+0], w.x, acc);
        acc = fmaf(feat[4*t+1], w.y, acc);
        acc = fmaf(feat[4*t+2], w.z, acc);
        acc = fmaf(feat[4*t+3], w.w, acc);
      }
    } else {
#pragma unroll
      for (int f = 0; f < 60; ++f) acc = fmaf(feat[f], Wsrc[f * 48 + j], acc);
    }
    h[q] = acc;
  }

  // ---- LayerNorm over the 48 outputs of this row's trajectory ----
  const float s1 = rsum16(h[0] + h[1] + h[2]);
  const float s2 = rsum16(fmaf(h[0], h[0], fmaf(h[1], h[1], h[2] * h[2])));
  const float mu  = s1 * (1.f / 48.f);
  const float var = fmaf(-mu, mu, s2 * (1.f / 48.f));
  const float rstd = __builtin_amdgcn_rsqf(var + 1e-5f);

  if (bvalid) {
#pragma unroll
    for (int q = 0; q < 3; ++q) {
      const int j = q * 16 + s;
      float x = (h[q] - mu) * rstd * lnw[j] + lnb[j];
      // tanh-form GELU (<=1e-3 abs dev from exact erf form)
      float x2 = x * x;
      float u  = 0.7978845608f * x * fmaf(0.044715f, x2, 1.f);
      float e  = __builtin_amdgcn_exp2f(u * 2.885390082f);   // e^{2u}
      float th = fmaf(-2.f, frcp(1.f + e), 1.f);
      out[(size_t)b * 48 + j] = 0.5f * x * (1.f + th);
    }
  }
}

extern "C" void kernel_launch(void* const* d_in, const int* in_sizes, int n_in,
                              void* d_out, int out_size, void* d_ws, size_t ws_size,
                              hipStream_t stream)
{
  const float* coords = (const float*)d_in[0];
  const int*   lengths= (const int*)d_in[1];
  const float* W      = (const float*)d_in[2];
  const float* bias   = (const float*)d_in[3];
  const float* lnw    = (const float*)d_in[4];
  const float* lnb    = (const float*)d_in[5];
  float* out = (float*)d_out;

  const int B = in_sizes[1];
  const int blocks = (B + 15) / 16;   // 16 trajectories per 256-thread block

  if (ws_size >= (size_t)(60 * 48 * sizeof(float))) {
    float* Wt = (float*)d_ws;
    transpose_w<<<12, 256, 0, stream>>>(W, Wt);
    traj_kernel<true><<<blocks, 256, 0, stream>>>(coords, lengths, Wt, bias, lnw, lnb, out, B);
  } else {
    traj_kernel<false><<<blocks, 256, 0, stream>>>(coords, lengths, W, bias, lnw, lnb, out, B);
  }
}